// Round 9
// baseline (202.479 us; speedup 1.0000x reference)
//
#include <hip/hip_runtime.h>
#include <hip/hip_bf16.h>

// B=2, S=2048, D=1024, H=16, HD=64.  out = proj(attn(qkv(x))), fp32 I/O,
// bf16 MFMA internally.
//
// R9: barrier-drain amortization. GEMMs use BK=64 staged as two 32-k
// half-planes (halves the per-block barrier count; keeps 64B async16 rows
// and the m97 conflict profile). Attention uses 512-thread blocks (128
// queries) so each staged chunk feeds 8 waves.

typedef __attribute__((ext_vector_type(8))) short short8;
typedef __attribute__((ext_vector_type(4))) float float4v;

#define S_LEN 2048
#define NHEAD 16
#define HDIM  64
#define DMODEL 1024

__device__ __forceinline__ unsigned short f2bf(float f) {
    union { float f; unsigned u; } v; v.f = f;
    unsigned r = v.u + 0x7FFF + ((v.u >> 16) & 1);   // RNE
    return (unsigned short)(r >> 16);
}

__device__ __forceinline__ unsigned fbits_rn(float f) {  // bits+0x8000: RN pack
    union { float f; unsigned u; } v; v.f = f;
    return v.u + 0x8000u;
}

__device__ __forceinline__ void async16(const void* g, const void* l) {
    __builtin_amdgcn_global_load_lds(
        (const __attribute__((address_space(1))) unsigned int*)g,
        (__attribute__((address_space(3))) unsigned int*)l, 16, 0, 0);
}

// ---------------------------------------------------------------------------
__global__ void f32_to_bf16_v4(const float4* __restrict__ in,
                               ushort4* __restrict__ out, int n4) {
    int i = blockIdx.x * blockDim.x + threadIdx.x;
    if (i < n4) {
        float4 v = in[i];
        ushort4 o;
        o.x = f2bf(v.x); o.y = f2bf(v.y); o.z = f2bf(v.z); o.w = f2bf(v.w);
        out[i] = o;
    }
}

// Both weight matrices, one launch. in[K][N] fp32 -> out[N][K] bf16.
__global__ __launch_bounds__(256) void w_transpose_bf16(
    const float* __restrict__ Wqkv, const float* __restrict__ Wproj,
    unsigned short* __restrict__ outQ, unsigned short* __restrict__ outP) {
    __shared__ float t[64][65];
    const float* in; unsigned short* out; int N, bxl;
    if (blockIdx.x < 48) { in = Wqkv;  out = outQ; N = 3072; bxl = blockIdx.x; }
    else                 { in = Wproj; out = outP; N = 1024; bxl = blockIdx.x - 48; }
    const int K = 1024;
    const int kb = blockIdx.y * 64, nb = bxl * 64;
    const int tid = threadIdx.x;
    const int r0 = tid >> 4, c0 = (tid & 15) * 4;
#pragma unroll
    for (int g = 0; g < 4; g++) {
        float4 v = *(const float4*)(in + (size_t)(kb + g * 16 + r0) * N + nb + c0);
        t[g * 16 + r0][c0 + 0] = v.x; t[g * 16 + r0][c0 + 1] = v.y;
        t[g * 16 + r0][c0 + 2] = v.z; t[g * 16 + r0][c0 + 3] = v.w;
    }
    __syncthreads();
#pragma unroll
    for (int g = 0; g < 4; g++) {
        int n = g * 16 + r0;
        ushort4 o;
        o.x = f2bf(t[c0 + 0][n]); o.y = f2bf(t[c0 + 1][n]);
        o.z = f2bf(t[c0 + 2][n]); o.w = f2bf(t[c0 + 3][n]);
        *(ushort4*)(out + (size_t)(nb + n) * K + kb + c0) = o;
    }
}

// V [bh][s][64] -> Vt [bh][64][S] with key-group swizzle g -> g ^ (hd&15)
// applied within each 16-group (128B) window.
__global__ __launch_bounds__(256) void v_transpose_sw(
    const unsigned short* __restrict__ V, unsigned short* __restrict__ Vt) {
    __shared__ unsigned short t[64 * 68];
    const int bh = blockIdx.y;
    const int s0 = blockIdx.x * 64;
    const int tid = threadIdx.x;
    const int r = tid >> 2;          // load: s-row; store: hd-row
    const int c4 = tid & 3;
    const size_t base = (size_t)bh * S_LEN * HDIM;
    union { uint4 v[2]; unsigned short u[16]; } d;
    const unsigned short* src = V + base + (size_t)(s0 + r) * HDIM + c4 * 16;
    d.v[0] = *(const uint4*)(src);
    d.v[1] = *(const uint4*)(src + 8);
#pragma unroll
    for (int j = 0; j < 16; j++) t[(c4 * 16 + j) * 68 + r] = d.u[j];  // t[hd][s]
    __syncthreads();
    const int h4 = r & 15;
    const unsigned short* pl = t + r * 68 + c4 * 16;
    unsigned short* po = Vt + base + (size_t)r * S_LEN + s0
                         + (((c4 * 4) ^ (h4 & 12)) << 2);
    uint2 ug[4];
#pragma unroll
    for (int i = 0; i < 4; i++)
        ug[i ^ (h4 & 3)] = *(const uint2*)(pl + i * 4);
    uint4 w0; w0.x = ug[0].x; w0.y = ug[0].y; w0.z = ug[1].x; w0.w = ug[1].y;
    uint4 w1; w1.x = ug[2].x; w1.y = ug[2].y; w1.z = ug[3].x; w1.w = ug[3].y;
    *(uint4*)(po) = w0;
    *(uint4*)(po + 8) = w1;
}

// ---------------------------------------------------------------------------
// QKV GEMM: C[M,3072] = A[M,1024]*Bt[3072,1024]^T + bias.  BK=64 staged as
// two 32-k half-planes (As/Bs halves of 128x32 each).  Epilogue: pair-packed
// ds_write_b32 into 128x132 tile, line-coalesced stores.
// Outputs: Q(scaled)/V [bh][s][64], K2 [bh][2][s][32].
// ---------------------------------------------------------------------------
#define QSCALE 0.18033688f   // 0.125 * log2(e), folded into Q

__global__ __launch_bounds__(256) void gemm_qkv_kernel(
    const unsigned short* __restrict__ A,
    const unsigned short* __restrict__ Bt,
    const float* __restrict__ bias,
    unsigned short* __restrict__ out_q,
    unsigned short* __restrict__ out_k,
    unsigned short* __restrict__ out_v,
    int M, int N, int K)
{
    __shared__ unsigned short smem[128 * 132];   // 33792B; As|Bs then epilogue
    unsigned short* As = smem;            // halves at +0, +4096 shorts
    unsigned short* Bs = smem + 8192;

    const int tid  = threadIdx.x;
    const int lane = tid & 63;
    const int wave = tid >> 6;
    const int quad = lane >> 4;
    const int l16  = lane & 15;

    const int m0 = blockIdx.y * 128;
    const int n0 = blockIdx.x * 128;
    const int wm = (wave >> 1) * 64;
    const int wn = (wave & 1) * 64;

    float4v acc[4][4];
#pragma unroll
    for (int i = 0; i < 4; i++)
#pragma unroll
        for (int j = 0; j < 4; j++) acc[i][j] = (float4v){0.f, 0.f, 0.f, 0.f};

    const int srow = lane >> 2;
    const int scol = (lane & 3) * 8;

    for (int k0 = 0; k0 < K; k0 += 64) {
        __syncthreads();
#pragma unroll
        for (int kk = 0; kk < 2; kk++)
#pragma unroll
            for (int it = 0; it < 2; it++) {
                const int rg = it * 64 + wave * 16;
                async16(A  + (size_t)(m0 + rg + srow) * K + k0 + kk * 32 + scol,
                        (const char*)(As + kk * 4096) + rg * 64);
                async16(Bt + (size_t)(n0 + rg + srow) * K + k0 + kk * 32 + scol,
                        (const char*)(Bs + kk * 4096) + rg * 64);
            }
        __syncthreads();

#pragma unroll
        for (int kk = 0; kk < 2; kk++) {
            short8 af[4], bf[4];
#pragma unroll
            for (int mt = 0; mt < 4; mt++)
                af[mt] = *(const short8*)(As + kk * 4096
                                          + (wm + mt * 16 + l16) * 32 + quad * 8);
#pragma unroll
            for (int nt = 0; nt < 4; nt++)
                bf[nt] = *(const short8*)(Bs + kk * 4096
                                          + (wn + nt * 16 + l16) * 32 + quad * 8);
#pragma unroll
            for (int mt = 0; mt < 4; mt++)
#pragma unroll
                for (int nt = 0; nt < 4; nt++)
                    acc[mt][nt] = __builtin_amdgcn_mfma_f32_16x16x32_bf16(
                        af[mt], bf[nt], acc[mt][nt], 0, 0, 0);
        }
    }

    // ---- epilogue: pair-packed b32 writes ----
    __syncthreads();
#pragma unroll
    for (int nt = 0; nt < 4; nt++) {
        const int col = n0 + wn + nt * 16 + l16;
        const float sc = ((col >> 10) == 0) ? QSCALE : 1.0f;
        const float bia = bias[col] * sc;
        const int cold = (wn + nt * 16 + l16) >> 1;
#pragma unroll
        for (int mt = 0; mt < 4; mt++)
#pragma unroll
            for (int r = 0; r < 4; r++) {
                unsigned fb = fbits_rn(acc[mt][nt][r] * sc + bia);
                unsigned fbp = (unsigned)__shfl_xor((int)fb, 1, 64);
                unsigned pd = (l16 & 1)
                    ? __builtin_amdgcn_perm(fb, fbp, 0x07060302)
                    : __builtin_amdgcn_perm(fbp, fb, 0x07060302);
                const int rowl = wm + mt * 16 + quad * 4 + r;
                *((unsigned*)smem + rowl * 66 + cold) = pd;
            }
    }
    __syncthreads();

    // ---- store phase: full-line coalesced ----
#pragma unroll
    for (int ps = 0; ps < 8; ps++) {
        const int row = ps * 16 + (tid >> 4);
        const int pc  = tid & 15;
        const int col0 = pc * 8;
        const int haf = col0 >> 6;
        const int cb = n0 + haf * 64;
        const int part = cb >> 10;
        const int h = (cb & 1023) >> 6;
        const int gr = m0 + row;
        const int b = gr >> 11, s = gr & 2047;
        const size_t bhI = (size_t)(b * NHEAD + h);
        const unsigned short* pl = smem + row * 132 + col0;
        uint2 a = *(const uint2*)(pl);
        uint2 bb = *(const uint2*)(pl + 4);
        uint4 w; w.x = a.x; w.y = a.y; w.z = bb.x; w.w = bb.y;
        unsigned short* po;
        if (part == 1) {
            const int plane = (col0 & 63) >> 5;
            po = out_k + ((bhI * 2 + plane) * S_LEN + s) * 32 + (col0 & 31);
        } else {
            unsigned short* dst = (part == 0) ? out_q : out_v;
            po = dst + (bhI * S_LEN + s) * HDIM + (col0 & 63);
        }
        *(uint4*)po = w;
    }
}

// ---------------------------------------------------------------------------
// proj GEMM: out[M,1024] fp32 = ctx[M,1024]*Wt^T + bias.  64x128 tile, BK=64
// as two half-planes.  512 blocks.
// ---------------------------------------------------------------------------
__global__ __launch_bounds__(256) void gemm_proj_kernel(
    const unsigned short* __restrict__ A,
    const unsigned short* __restrict__ Bt,
    const float* __restrict__ bias,
    float* __restrict__ out_f,
    int M, int N, int K)
{
    __shared__ unsigned short smem[12288];   // As 2x64x32 | Bs 2x128x32 = 24KB
    unsigned short* As = smem;               // halves at +0, +2048
    unsigned short* Bs = smem + 4096;        // halves at +0, +4096

    const int tid  = threadIdx.x;
    const int lane = tid & 63;
    const int wave = tid >> 6;
    const int quad = lane >> 4;
    const int l16  = lane & 15;

    const int m0 = blockIdx.y * 64;
    const int n0 = blockIdx.x * 128;
    const int wm = (wave >> 1) * 32;
    const int wn = (wave & 1) * 64;

    float4v acc[2][4];
#pragma unroll
    for (int i = 0; i < 2; i++)
#pragma unroll
        for (int j = 0; j < 4; j++) acc[i][j] = (float4v){0.f, 0.f, 0.f, 0.f};

    const int srow = lane >> 2;
    const int scol = (lane & 3) * 8;

    for (int k0 = 0; k0 < K; k0 += 64) {
        __syncthreads();
#pragma unroll
        for (int kk = 0; kk < 2; kk++) {
            async16(A + (size_t)(m0 + wave * 16 + srow) * K + k0 + kk * 32 + scol,
                    (const char*)(As + kk * 2048) + wave * 1024);
#pragma unroll
            for (int it = 0; it < 2; it++) {
                const int rg = it * 64 + wave * 16;
                async16(Bt + (size_t)(n0 + rg + srow) * K + k0 + kk * 32 + scol,
                        (const char*)(Bs + kk * 4096) + rg * 64);
            }
        }
        __syncthreads();

#pragma unroll
        for (int kk = 0; kk < 2; kk++) {
            short8 af[2], bf[4];
#pragma unroll
            for (int mt = 0; mt < 2; mt++)
                af[mt] = *(const short8*)(As + kk * 2048
                                          + (wm + mt * 16 + l16) * 32 + quad * 8);
#pragma unroll
            for (int nt = 0; nt < 4; nt++)
                bf[nt] = *(const short8*)(Bs + kk * 4096
                                          + (wn + nt * 16 + l16) * 32 + quad * 8);
#pragma unroll
            for (int mt = 0; mt < 2; mt++)
#pragma unroll
                for (int nt = 0; nt < 4; nt++)
                    acc[mt][nt] = __builtin_amdgcn_mfma_f32_16x16x32_bf16(
                        af[mt], bf[nt], acc[mt][nt], 0, 0, 0);
        }
    }

#pragma unroll
    for (int nt = 0; nt < 4; nt++) {
        const int col = n0 + wn + nt * 16 + l16;
        const float bia = bias[col];
#pragma unroll
        for (int mt = 0; mt < 2; mt++) {
            const int rowb = m0 + wm + mt * 16 + quad * 4;
#pragma unroll
            for (int r = 0; r < 4; r++)
                out_f[(size_t)(rowb + r) * N + col] = acc[mt][nt][r] + bia;
        }
    }
}

// ---------------------------------------------------------------------------
// Attention: 512 blocks x 512 threads (8 waves = 128 queries), 64-key chunks
// double-buffered; each staged chunk feeds 8 waves.  bh == bx (mod 32) pins
// heads to XCDs; qb pairing makes co-resident block pairs equal-work.
// ---------------------------------------------------------------------------
__global__ __launch_bounds__(512) void attn4_kernel(
    const unsigned short* __restrict__ Q,    // [bh][s][64] pre-scaled
    const unsigned short* __restrict__ K2,   // [bh][2][s][32]
    const unsigned short* __restrict__ Vt,   // [bh][64][S] swizzled
    unsigned short* __restrict__ ctx)        // [B, S, H*64]
{
    __shared__ unsigned short Ks[2][128 * 32];
    __shared__ unsigned short Vs[2][64 * 64];

    const int tid  = threadIdx.x;
    const int lane = tid & 63;
    const int wave = tid >> 6;
    const int quad = lane >> 4;
    const int l16  = lane & 15;

    const int bx = blockIdx.x;
    const int bh = bx & 31;
    const int j  = bx >> 5;                     // 0..15
    const int qb = (j < 8) ? (15 - j) : (j - 8);
    const int q0 = qb * 128 + wave * 16;
    const int nch = 2 * qb + 2;

    const size_t baseQ = (size_t)bh * S_LEN * HDIM;
    const size_t baseK = (size_t)bh * 2 * S_LEN * 32;
    const size_t baseV = (size_t)bh * HDIM * S_LEN;

    // staging source addresses (per-lane global, wave-uniform LDS base)
    const int krw = wave * 16 + (lane >> 2);    // 0..127 = h*64 + key
    const int kcol = (lane & 3) * 8;
    const int vrw = wave * 8 + (lane >> 3);     // 0..63 = hd
    const int vcol = (lane & 7) * 8;

    short8 qf[2];
#pragma unroll
    for (int h = 0; h < 2; h++)
        qf[h] = *(const short8*)(Q + baseQ + (size_t)(q0 + l16) * HDIM
                                 + h * 32 + quad * 8);

    float4v o[4];
#pragma unroll
    for (int nt = 0; nt < 4; nt++) o[nt] = (float4v){0.f, 0.f, 0.f, 0.f};
    float lsum = 0.f;

#define ATTN_STAGE(buf, kb0)                                                   \
    do {                                                                       \
        async16(K2 + baseK + ((size_t)(krw >> 6) * S_LEN + (kb0) + (krw & 63)) \
                    * 32 + kcol,                                               \
                (const char*)Ks[buf] + wave * 1024);                           \
        async16(Vt + baseV + (size_t)vrw * S_LEN + (kb0) + vcol,               \
                (const char*)Vs[buf] + wave * 1024);                           \
    } while (0)

    ATTN_STAGE(0, 0);

    for (int c = 0; c < nch; c++) {
        const int buf = c & 1;
        __syncthreads();
        if (c + 1 < nch) ATTN_STAGE(buf ^ 1, (c + 1) * 64);

        const int kb0 = c * 64;
        short8 kf[4][2];
#pragma unroll
        for (int kt = 0; kt < 4; kt++)
#pragma unroll
            for (int h = 0; h < 2; h++)
                kf[kt][h] = *(const short8*)&Ks[buf][(h * 64 + kt * 16 + l16) * 32
                                                     + quad * 8];
        float4v st[4];
#pragma unroll
        for (int kt = 0; kt < 4; kt++) {
            st[kt] = __builtin_amdgcn_mfma_f32_16x16x32_bf16(
                kf[kt][0], qf[0], (float4v){0.f, 0.f, 0.f, 0.f}, 0, 0, 0);
            st[kt] = __builtin_amdgcn_mfma_f32_16x16x32_bf16(
                kf[kt][1], qf[1], st[kt], 0, 0, 0);
        }
        const bool needm = (kb0 + 63 > q0);   // wave-uniform mask gate
        const int qpos = q0 + l16;
        float p[4][4];
#pragma unroll
        for (int kt = 0; kt < 4; kt++)
#pragma unroll
            for (int r = 0; r < 4; r++) {
                float x = st[kt][r];
                if (needm) {
                    int kpos = kb0 + kt * 16 + quad * 4 + r;
                    x = (kpos <= qpos) ? x : -1e30f;
                }
                p[kt][r] = __builtin_amdgcn_exp2f(x);
                lsum += p[kt][r];
            }

        unsigned pk[4][2];
#pragma unroll
        for (int kt = 0; kt < 4; kt++)
#pragma unroll
            for (int jj = 0; jj < 2; jj++)
                pk[kt][jj] = __builtin_amdgcn_perm(
                    fbits_rn(p[kt][2 * jj + 1]), fbits_rn(p[kt][2 * jj]),
                    0x07060302);
        union { unsigned u[4]; short8 s; } pf[2];
#pragma unroll
        for (int kk = 0; kk < 2; kk++)
#pragma unroll
            for (int pp = 0; pp < 4; pp++)
                pf[kk].u[pp] = pk[kk * 2 + (pp >> 1)][pp & 1];

#pragma unroll
        for (int nt = 0; nt < 4; nt++) {
            union { ushort4 h[2]; short8 s; } vf[2];
#pragma unroll
            for (int kt = 0; kt < 4; kt++)
                vf[kt >> 1].h[kt & 1] = *(const ushort4*)&Vs[buf][
                    (nt * 16 + l16) * 64 + (((kt * 4 + quad) ^ l16) << 2)];
            o[nt] = __builtin_amdgcn_mfma_f32_16x16x32_bf16(
                pf[0].s, vf[0].s, o[nt], 0, 0, 0);
            o[nt] = __builtin_amdgcn_mfma_f32_16x16x32_bf16(
                pf[1].s, vf[1].s, o[nt], 0, 0, 0);
        }
    }
#undef ATTN_STAGE

    float l = lsum;
    l += __shfl_xor(l, 16, 64);
    l += __shfl_xor(l, 32, 64);
    const float linv = 1.f / l;
    float lr[4];
#pragma unroll
    for (int r = 0; r < 4; r++) lr[r] = __shfl(linv, quad * 4 + r, 64);

    const int b = bh >> 4, h = bh & 15;
#pragma unroll
    for (int r = 0; r < 4; r++) {
        const int s = q0 + quad * 4 + r;
        const size_t off = ((size_t)(b * S_LEN + s)) * DMODEL + h * HDIM;
#pragma unroll
        for (int nt = 0; nt < 4; nt++)
            ctx[off + nt * 16 + l16] = f2bf(o[nt][r] * lr[r]);
    }
}

extern "C" void kernel_launch(void* const* d_in, const int* in_sizes, int n_in,
                              void* d_out, int out_size, void* d_ws, size_t ws_size,
                              hipStream_t stream) {
    const float* x     = (const float*)d_in[0];
    const float* Wqkv  = (const float*)d_in[1];
    const float* bqkv  = (const float*)d_in[2];
    const float* Wproj = (const float*)d_in[3];
    const float* bproj = (const float*)d_in[4];
    float* out = (float*)d_out;

    const int M  = 2 * S_LEN;     // 4096
    const int N1 = 3 * DMODEL;    // 3072
    const int K  = DMODEL;        // 1024

    unsigned short* x_bf    = (unsigned short*)d_ws;
    unsigned short* wqkv_t  = x_bf   + (size_t)M * K;
    unsigned short* wproj_t = wqkv_t + (size_t)K * N1;
    unsigned short* q_bf    = wproj_t + (size_t)K * DMODEL;
    unsigned short* k_bf    = q_bf   + (size_t)M * DMODEL;
    unsigned short* v_bf    = k_bf   + (size_t)M * DMODEL;
    unsigned short* ctx_bf  = v_bf   + (size_t)M * DMODEL;
    unsigned short* vt_bf   = x_bf;   // alias: x_bf dead after QKV GEMM

    {
        int n4 = (M * K) / 4;
        f32_to_bf16_v4<<<n4 / 256, 256, 0, stream>>>((const float4*)x,
                                                     (ushort4*)x_bf, n4);
    }
    {
        dim3 g(64, 16);
        w_transpose_bf16<<<g, 256, 0, stream>>>(Wqkv, Wproj, wqkv_t, wproj_t);
    }

    dim3 g1(N1 / 128, M / 128);   // 24 x 32
    gemm_qkv_kernel<<<g1, 256, 0, stream>>>(x_bf, wqkv_t, bqkv,
                                            q_bf, k_bf, v_bf, M, N1, K);

    {
        dim3 g(S_LEN / 64, 2 * NHEAD);  // 32 x 32
        v_transpose_sw<<<g, 256, 0, stream>>>(v_bf, vt_bf);
    }

    attn4_kernel<<<512, 512, 0, stream>>>(q_bf, k_bf, vt_bf, ctx_bf);

    dim3 g3(DMODEL / 128, M / 64);   // 8 x 64
    gemm_proj_kernel<<<g3, 256, 0, stream>>>(ctx_bf, wproj_t, bproj, out,
                                             M, DMODEL, K);
}

// Round 11
// 188.051 us; speedup vs baseline: 1.0767x; 1.0767x over previous
//
#include <hip/hip_runtime.h>
#include <hip/hip_bf16.h>

// B=2, S=2048, D=1024, H=16, HD=64.  out = proj(attn(qkv(x))), fp32 I/O,
// bf16 MFMA internally.
//
// R11 = R10 with the v_pack clobber bug fixed.
// Attention is LDS-free / barrier-free: K and V live in fragment-major
// packed layouts so every MFMA fragment is one coalesced global_load_dwordx4
// from L2:
//   Kp[bh][chunk32][kt4][h2][lane64][8]   (written directly by QKV epilogue)
//   Vp[bh][chunk32][nt4][kk2][lane64][8]  (pack kernel)
// Waves are fully independent -> compiler software-pipelines chunks with
// fine-grained vmcnt (no vmcnt(0)+barrier drain).

typedef __attribute__((ext_vector_type(8))) short short8;
typedef __attribute__((ext_vector_type(4))) float float4v;

#define S_LEN 2048
#define NHEAD 16
#define HDIM  64
#define DMODEL 1024

__device__ __forceinline__ unsigned short f2bf(float f) {
    union { float f; unsigned u; } v; v.f = f;
    unsigned r = v.u + 0x7FFF + ((v.u >> 16) & 1);   // RNE
    return (unsigned short)(r >> 16);
}

__device__ __forceinline__ unsigned fbits_rn(float f) {  // bits+0x8000: RN pack
    union { float f; unsigned u; } v; v.f = f;
    return v.u + 0x8000u;
}

__device__ __forceinline__ void async16(const void* g, const void* l) {
    __builtin_amdgcn_global_load_lds(
        (const __attribute__((address_space(1))) unsigned int*)g,
        (__attribute__((address_space(3))) unsigned int*)l, 16, 0, 0);
}

// ---------------------------------------------------------------------------
__global__ void f32_to_bf16_v4(const float4* __restrict__ in,
                               ushort4* __restrict__ out, int n4) {
    int i = blockIdx.x * blockDim.x + threadIdx.x;
    if (i < n4) {
        float4 v = in[i];
        ushort4 o;
        o.x = f2bf(v.x); o.y = f2bf(v.y); o.z = f2bf(v.z); o.w = f2bf(v.w);
        out[i] = o;
    }
}

// Both weight matrices, one launch. in[K][N] fp32 -> out[N][K] bf16.
__global__ __launch_bounds__(256) void w_transpose_bf16(
    const float* __restrict__ Wqkv, const float* __restrict__ Wproj,
    unsigned short* __restrict__ outQ, unsigned short* __restrict__ outP) {
    __shared__ float t[64][65];
    const float* in; unsigned short* out; int N, bxl;
    if (blockIdx.x < 48) { in = Wqkv;  out = outQ; N = 3072; bxl = blockIdx.x; }
    else                 { in = Wproj; out = outP; N = 1024; bxl = blockIdx.x - 48; }
    const int K = 1024;
    const int kb = blockIdx.y * 64, nb = bxl * 64;
    const int tid = threadIdx.x;
    const int r0 = tid >> 4, c0 = (tid & 15) * 4;
#pragma unroll
    for (int g = 0; g < 4; g++) {
        float4 v = *(const float4*)(in + (size_t)(kb + g * 16 + r0) * N + nb + c0);
        t[g * 16 + r0][c0 + 0] = v.x; t[g * 16 + r0][c0 + 1] = v.y;
        t[g * 16 + r0][c0 + 2] = v.z; t[g * 16 + r0][c0 + 3] = v.w;
    }
    __syncthreads();
#pragma unroll
    for (int g = 0; g < 4; g++) {
        int n = g * 16 + r0;
        ushort4 o;
        o.x = f2bf(t[c0 + 0][n]); o.y = f2bf(t[c0 + 1][n]);
        o.z = f2bf(t[c0 + 2][n]); o.w = f2bf(t[c0 + 3][n]);
        *(ushort4*)(out + (size_t)(nb + n) * K + kb + c0) = o;
    }
}

// V [bh][s][64] -> Vp [bh][chunk][nt][kk][lane][8]  (fragment-major).
// Fragment semantics (R3-verified): vf[nt][kk] lane(quad,l16), short j:
//   key = (kk*2 + (j>>2))*16 + quad*4 + (j&3),  hd = nt*16 + l16.
__global__ __launch_bounds__(256) void v_pack(
    const unsigned short* __restrict__ V, unsigned short* __restrict__ Vp) {
    __shared__ unsigned short t[64 * 68];
    const int bh = blockIdx.y;
    const int c0 = blockIdx.x;          // 64-key chunk
    const int s0 = c0 * 64;
    const int tid = threadIdx.x;
    const int r = tid >> 2, c4 = tid & 3;
    const size_t base = (size_t)bh * S_LEN * HDIM;
    union { uint4 v[2]; unsigned short u[16]; } d;
    const unsigned short* src = V + base + (size_t)(s0 + r) * HDIM + c4 * 16;
    d.v[0] = *(const uint4*)(src);
    d.v[1] = *(const uint4*)(src + 8);
#pragma unroll
    for (int j = 0; j < 16; j++) t[r * 68 + c4 * 16 + j] = d.u[j];  // t[key][hd]
    __syncthreads();
    // 512 16B pieces, 2 per thread (consecutive lanes -> 32B/thread store)
    unsigned short* outb = Vp + ((size_t)(bh * 32 + c0)) * 4096;
#pragma unroll
    for (int pi = 0; pi < 2; pi++) {
        const int p = tid * 2 + pi;
        const int lane = p & 63, kk = (p >> 6) & 1, nt = p >> 7;
        const int q = lane >> 4, l = lane & 15;
        union { ushort4 v[2]; unsigned short u[8]; } w;
#pragma unroll
        for (int j = 0; j < 8; j++) {
            const int key = (kk * 2 + (j >> 2)) * 16 + q * 4 + (j & 3);
            w.u[j] = t[key * 68 + nt * 16 + l];
        }
        unsigned short* po = outb + ((nt * 2 + kk) * 64 + lane) * 8;
        *(ushort4*)(po) = w.v[0];
        *(ushort4*)(po + 4) = w.v[1];
    }
}

// ---------------------------------------------------------------------------
// QKV GEMM: C[M,3072] = A[M,1024]*Bt[3072,1024]^T + bias.  BK=64 (two 32-k
// half-planes).  Epilogue: pair-packed ds_write_b32 into 128x132 tile, then
// line-coalesced 16B stores: Q/V -> [bh][s][64], K -> Kp fragment-major.
// ---------------------------------------------------------------------------
#define QSCALE 0.18033688f   // 0.125 * log2(e), folded into Q

__global__ __launch_bounds__(256) void gemm_qkv_kernel(
    const unsigned short* __restrict__ A,
    const unsigned short* __restrict__ Bt,
    const float* __restrict__ bias,
    unsigned short* __restrict__ out_q,
    unsigned short* __restrict__ out_kp,
    unsigned short* __restrict__ out_v,
    int M, int N, int K)
{
    __shared__ unsigned short smem[128 * 132];
    unsigned short* As = smem;            // halves at +0, +4096 shorts
    unsigned short* Bs = smem + 8192;

    const int tid  = threadIdx.x;
    const int lane = tid & 63;
    const int wave = tid >> 6;
    const int quad = lane >> 4;
    const int l16  = lane & 15;

    const int m0 = blockIdx.y * 128;
    const int n0 = blockIdx.x * 128;
    const int wm = (wave >> 1) * 64;
    const int wn = (wave & 1) * 64;

    float4v acc[4][4];
#pragma unroll
    for (int i = 0; i < 4; i++)
#pragma unroll
        for (int j = 0; j < 4; j++) acc[i][j] = (float4v){0.f, 0.f, 0.f, 0.f};

    const int srow = lane >> 2;
    const int scol = (lane & 3) * 8;

    for (int k0 = 0; k0 < K; k0 += 64) {
        __syncthreads();
#pragma unroll
        for (int kk = 0; kk < 2; kk++)
#pragma unroll
            for (int it = 0; it < 2; it++) {
                const int rg = it * 64 + wave * 16;
                async16(A  + (size_t)(m0 + rg + srow) * K + k0 + kk * 32 + scol,
                        (const char*)(As + kk * 4096) + rg * 64);
                async16(Bt + (size_t)(n0 + rg + srow) * K + k0 + kk * 32 + scol,
                        (const char*)(Bs + kk * 4096) + rg * 64);
            }
        __syncthreads();

#pragma unroll
        for (int kk = 0; kk < 2; kk++) {
            short8 af[4], bf[4];
#pragma unroll
            for (int mt = 0; mt < 4; mt++)
                af[mt] = *(const short8*)(As + kk * 4096
                                          + (wm + mt * 16 + l16) * 32 + quad * 8);
#pragma unroll
            for (int nt = 0; nt < 4; nt++)
                bf[nt] = *(const short8*)(Bs + kk * 4096
                                          + (wn + nt * 16 + l16) * 32 + quad * 8);
#pragma unroll
            for (int mt = 0; mt < 4; mt++)
#pragma unroll
                for (int nt = 0; nt < 4; nt++)
                    acc[mt][nt] = __builtin_amdgcn_mfma_f32_16x16x32_bf16(
                        af[mt], bf[nt], acc[mt][nt], 0, 0, 0);
        }
    }

    // ---- epilogue: pair-packed b32 writes ----
    __syncthreads();
#pragma unroll
    for (int nt = 0; nt < 4; nt++) {
        const int col = n0 + wn + nt * 16 + l16;
        const float sc = ((col >> 10) == 0) ? QSCALE : 1.0f;
        const float bia = bias[col] * sc;
        const int cold = (wn + nt * 16 + l16) >> 1;
#pragma unroll
        for (int mt = 0; mt < 4; mt++)
#pragma unroll
            for (int r = 0; r < 4; r++) {
                unsigned fb = fbits_rn(acc[mt][nt][r] * sc + bia);
                unsigned fbp = (unsigned)__shfl_xor((int)fb, 1, 64);
                unsigned pd = (l16 & 1)
                    ? __builtin_amdgcn_perm(fb, fbp, 0x07060302)
                    : __builtin_amdgcn_perm(fbp, fb, 0x07060302);
                const int rowl = wm + mt * 16 + quad * 4 + r;
                *((unsigned*)smem + rowl * 66 + cold) = pd;
            }
    }
    __syncthreads();

    // ---- store phase: 16B pieces; K pieces go to fragment-major Kp ----
#pragma unroll
    for (int ps = 0; ps < 8; ps++) {
        const int row = ps * 16 + (tid >> 4);
        const int pc  = tid & 15;
        const int col0 = pc * 8;
        const int cb = n0 + (col0 >> 6) * 64;
        const int part = cb >> 10;
        const int hh = (cb & 1023) >> 6;           // head
        const int gr = m0 + row;
        const int b = gr >> 11, s = gr & 2047;
        const size_t bhI = (size_t)(b * NHEAD + hh);
        const unsigned short* pl = smem + row * 132 + col0;
        uint2 a = *(const uint2*)(pl);
        uint2 bb = *(const uint2*)(pl + 4);
        uint4 w; w.x = a.x; w.y = a.y; w.z = bb.x; w.w = bb.y;
        unsigned short* po;
        if (part == 1) {
            // Kp[bh][chunk=s>>6][kt=(s>>4)&3][h][lane=q*16+(s&15)][8]
            const int hd = col0 & 63;
            const int h = hd >> 5, q = (hd >> 3) & 3;
            po = out_kp + ((((bhI * 32 + (s >> 6)) * 4 + ((s >> 4) & 3)) * 2 + h)
                           * 64 + q * 16 + (s & 15)) * 8;
        } else {
            unsigned short* dst = (part == 0) ? out_q : out_v;
            po = dst + (bhI * S_LEN + s) * HDIM + (col0 & 63);
        }
        *(uint4*)po = w;
    }
}

// ---------------------------------------------------------------------------
// proj GEMM: out[M,1024] fp32 = ctx[M,1024]*Wt^T + bias.  64x128 tile, BK=64.
// ---------------------------------------------------------------------------
__global__ __launch_bounds__(256) void gemm_proj_kernel(
    const unsigned short* __restrict__ A,
    const unsigned short* __restrict__ Bt,
    const float* __restrict__ bias,
    float* __restrict__ out_f,
    int M, int N, int K)
{
    __shared__ unsigned short smem[12288];
    unsigned short* As = smem;               // halves at +0, +2048
    unsigned short* Bs = smem + 4096;        // halves at +0, +4096

    const int tid  = threadIdx.x;
    const int lane = tid & 63;
    const int wave = tid >> 6;
    const int quad = lane >> 4;
    const int l16  = lane & 15;

    const int m0 = blockIdx.y * 64;
    const int n0 = blockIdx.x * 128;
    const int wm = (wave >> 1) * 32;
    const int wn = (wave & 1) * 64;

    float4v acc[2][4];
#pragma unroll
    for (int i = 0; i < 2; i++)
#pragma unroll
        for (int j = 0; j < 4; j++) acc[i][j] = (float4v){0.f, 0.f, 0.f, 0.f};

    const int srow = lane >> 2;
    const int scol = (lane & 3) * 8;

    for (int k0 = 0; k0 < K; k0 += 64) {
        __syncthreads();
#pragma unroll
        for (int kk = 0; kk < 2; kk++) {
            async16(A + (size_t)(m0 + wave * 16 + srow) * K + k0 + kk * 32 + scol,
                    (const char*)(As + kk * 2048) + wave * 1024);
#pragma unroll
            for (int it = 0; it < 2; it++) {
                const int rg = it * 64 + wave * 16;
                async16(Bt + (size_t)(n0 + rg + srow) * K + k0 + kk * 32 + scol,
                        (const char*)(Bs + kk * 4096) + rg * 64);
            }
        }
        __syncthreads();

#pragma unroll
        for (int kk = 0; kk < 2; kk++) {
            short8 af[2], bf[4];
#pragma unroll
            for (int mt = 0; mt < 2; mt++)
                af[mt] = *(const short8*)(As + kk * 2048
                                          + (wm + mt * 16 + l16) * 32 + quad * 8);
#pragma unroll
            for (int nt = 0; nt < 4; nt++)
                bf[nt] = *(const short8*)(Bs + kk * 4096
                                          + (wn + nt * 16 + l16) * 32 + quad * 8);
#pragma unroll
            for (int mt = 0; mt < 2; mt++)
#pragma unroll
                for (int nt = 0; nt < 4; nt++)
                    acc[mt][nt] = __builtin_amdgcn_mfma_f32_16x16x32_bf16(
                        af[mt], bf[nt], acc[mt][nt], 0, 0, 0);
        }
    }

#pragma unroll
    for (int nt = 0; nt < 4; nt++) {
        const int col = n0 + wn + nt * 16 + l16;
        const float bia = bias[col];
#pragma unroll
        for (int mt = 0; mt < 2; mt++) {
            const int rowb = m0 + wm + mt * 16 + quad * 4;
#pragma unroll
            for (int r = 0; r < 4; r++)
                out_f[(size_t)(rowb + r) * N + col] = acc[mt][nt][r] + bia;
        }
    }
}

// ---------------------------------------------------------------------------
// Attention: LDS-free, barrier-free.  1024 blocks x 256 thr (4 independent
// waves, 16 queries each).  All K/V fragment loads are coalesced dwordx4
// from the packed layouts (L2-resident; bh = bx&31 pins heads to XCDs;
// qb = 31-(bx>>5) dispatches heavy blocks first).
// ---------------------------------------------------------------------------
__global__ __launch_bounds__(256) void attn5_kernel(
    const unsigned short* __restrict__ Q,    // [bh][s][64] pre-scaled
    const unsigned short* __restrict__ Kp,   // [bh][32][4][2][64][8]
    const unsigned short* __restrict__ Vp,   // [bh][32][4][2][64][8]
    unsigned short* __restrict__ ctx)        // [B, S, H*64]
{
    const int tid  = threadIdx.x;
    const int lane = tid & 63;
    const int wave = tid >> 6;
    const int quad = lane >> 4;
    const int l16  = lane & 15;

    const int bx = blockIdx.x;
    const int bh = bx & 31;
    const int qb = 31 - (bx >> 5);
    const int q0 = qb * 64 + wave * 16;
    const int nch = qb + 1;

    const size_t baseQ = (size_t)bh * S_LEN * HDIM;
    const unsigned short* kb_ = Kp + (size_t)bh * 32 * 4096;
    const unsigned short* vb_ = Vp + (size_t)bh * 32 * 4096;

    short8 qf[2];
#pragma unroll
    for (int h = 0; h < 2; h++)
        qf[h] = *(const short8*)(Q + baseQ + (size_t)(q0 + l16) * HDIM
                                 + h * 32 + quad * 8);

    float4v o[4];
#pragma unroll
    for (int nt = 0; nt < 4; nt++) o[nt] = (float4v){0.f, 0.f, 0.f, 0.f};
    float lsum = 0.f;

    for (int c = 0; c < nch; c++) {
        const unsigned short* kc = kb_ + (size_t)c * 4096;
        const unsigned short* vc = vb_ + (size_t)c * 4096;
        short8 kf[4][2], vf[4][2];
#pragma unroll
        for (int kt = 0; kt < 4; kt++)
#pragma unroll
            for (int h = 0; h < 2; h++)
                kf[kt][h] = *(const short8*)(kc + ((kt * 2 + h) * 64 + lane) * 8);
#pragma unroll
        for (int nt = 0; nt < 4; nt++)
#pragma unroll
            for (int kk = 0; kk < 2; kk++)
                vf[nt][kk] = *(const short8*)(vc + ((nt * 2 + kk) * 64 + lane) * 8);

        float4v st[4];
#pragma unroll
        for (int kt = 0; kt < 4; kt++) {
            st[kt] = __builtin_amdgcn_mfma_f32_16x16x32_bf16(
                kf[kt][0], qf[0], (float4v){0.f, 0.f, 0.f, 0.f}, 0, 0, 0);
            st[kt] = __builtin_amdgcn_mfma_f32_16x16x32_bf16(
                kf[kt][1], qf[1], st[kt], 0, 0, 0);
        }
        const bool lastc = (c == nch - 1);
        const int kb0 = c * 64;
        const int qpos = q0 + l16;
        float p[4][4];
#pragma unroll
        for (int kt = 0; kt < 4; kt++)
#pragma unroll
            for (int r = 0; r < 4; r++) {
                float x = st[kt][r];
                if (lastc) {
                    int kpos = kb0 + kt * 16 + quad * 4 + r;
                    x = (kpos <= qpos) ? x : -1e30f;
                }
                p[kt][r] = __builtin_amdgcn_exp2f(x);
                lsum += p[kt][r];
            }

        unsigned pk[4][2];
#pragma unroll
        for (int kt = 0; kt < 4; kt++)
#pragma unroll
            for (int j = 0; j < 2; j++)
                pk[kt][j] = __builtin_amdgcn_perm(
                    fbits_rn(p[kt][2 * j + 1]), fbits_rn(p[kt][2 * j]),
                    0x07060302);
        union { unsigned u[4]; short8 s; } pf[2];
#pragma unroll
        for (int kk = 0; kk < 2; kk++)
#pragma unroll
            for (int pp = 0; pp < 4; pp++)
                pf[kk].u[pp] = pk[kk * 2 + (pp >> 1)][pp & 1];

#pragma unroll
        for (int nt = 0; nt < 4; nt++) {
            o[nt] = __builtin_amdgcn_mfma_f32_16x16x32_bf16(
                pf[0].s, vf[nt][0], o[nt], 0, 0, 0);
            o[nt] = __builtin_amdgcn_mfma_f32_16x16x32_bf16(
                pf[1].s, vf[nt][1], o[nt], 0, 0, 0);
        }
    }

    float l = lsum;
    l += __shfl_xor(l, 16, 64);
    l += __shfl_xor(l, 32, 64);
    const float linv = 1.f / l;
    float lr[4];
#pragma unroll
    for (int r = 0; r < 4; r++) lr[r] = __shfl(linv, quad * 4 + r, 64);

    const int b = bh >> 4, h = bh & 15;
#pragma unroll
    for (int r = 0; r < 4; r++) {
        const int s = q0 + quad * 4 + r;
        const size_t off = ((size_t)(b * S_LEN + s)) * DMODEL + h * HDIM;
#pragma unroll
        for (int nt = 0; nt < 4; nt++)
            ctx[off + nt * 16 + l16] = f2bf(o[nt][r] * lr[r]);
    }
}

extern "C" void kernel_launch(void* const* d_in, const int* in_sizes, int n_in,
                              void* d_out, int out_size, void* d_ws, size_t ws_size,
                              hipStream_t stream) {
    const float* x     = (const float*)d_in[0];
    const float* Wqkv  = (const float*)d_in[1];
    const float* bqkv  = (const float*)d_in[2];
    const float* Wproj = (const float*)d_in[3];
    const float* bproj = (const float*)d_in[4];
    float* out = (float*)d_out;

    const int M  = 2 * S_LEN;     // 4096
    const int N1 = 3 * DMODEL;    // 3072
    const int K  = DMODEL;        // 1024

    unsigned short* x_bf    = (unsigned short*)d_ws;
    unsigned short* wqkv_t  = x_bf   + (size_t)M * K;
    unsigned short* wproj_t = wqkv_t + (size_t)K * N1;
    unsigned short* q_bf    = wproj_t + (size_t)K * DMODEL;
    unsigned short* kp_bf   = q_bf   + (size_t)M * DMODEL;
    unsigned short* v_bf    = kp_bf  + (size_t)M * DMODEL;
    unsigned short* ctx_bf  = v_bf   + (size_t)M * DMODEL;
    unsigned short* vp_bf   = x_bf;   // alias: x_bf dead after QKV GEMM

    {
        int n4 = (M * K) / 4;
        f32_to_bf16_v4<<<n4 / 256, 256, 0, stream>>>((const float4*)x,
                                                     (ushort4*)x_bf, n4);
    }
    {
        dim3 g(64, 16);
        w_transpose_bf16<<<g, 256, 0, stream>>>(Wqkv, Wproj, wqkv_t, wproj_t);
    }

    dim3 g1(N1 / 128, M / 128);   // 24 x 32
    gemm_qkv_kernel<<<g1, 256, 0, stream>>>(x_bf, wqkv_t, bqkv,
                                            q_bf, kp_bf, v_bf, M, N1, K);

    {
        dim3 g(S_LEN / 64, 2 * NHEAD);  // 32 x 32
        v_pack<<<g, 256, 0, stream>>>(v_bf, vp_bf);
    }

    attn5_kernel<<<1024, 256, 0, stream>>>(q_bf, kp_bf, vp_bf, ctx_bf);

    dim3 g3(DMODEL / 128, M / 64);   // 8 x 64
    gemm_proj_kernel<<<g3, 256, 0, stream>>>(ctx_bf, wproj_t, bproj, out,
                                             M, DMODEL, K);
}